// Round 2
// baseline (386.351 us; speedup 1.0000x reference)
//
#include <hip/hip_runtime.h>
#include <hip/hip_bf16.h>

#define D_DIM 128
#define AST 136   // padded LDS row stride (shorts) for the A tile
#define CST 132   // padded LDS row stride (shorts) for the C transpose

typedef __attribute__((ext_vector_type(8))) short short8v;
typedef __attribute__((ext_vector_type(4))) short short4v;
typedef __attribute__((ext_vector_type(4))) float floatx4;

__device__ __forceinline__ short f2bf(float x) {
    unsigned u = __builtin_bit_cast(unsigned, x);
    unsigned r = u + 0x7fff + ((u >> 16) & 1);   // RNE
    return (short)(r >> 16);
}
__device__ __forceinline__ float bflo(unsigned p) {
    return __builtin_bit_cast(float, p << 16);
}
__device__ __forceinline__ float bfhi(unsigned p) {
    return __builtin_bit_cast(float, p & 0xffff0000u);
}

// ---------------- CSR build ----------------

__global__ void zero_cnt_kernel(int* __restrict__ cnt, int n) {
    int i = blockIdx.x * blockDim.x + threadIdx.x;
    if (i < n) cnt[i] = 0;
}

// packed[v*16+j] default: src = v (self row, L1-hot at gather time), weight = 0
__global__ void packed_init_kernel(int2* __restrict__ packed, int n16) {
    int i = blockIdx.x * blockDim.x + threadIdx.x;
    if (i < n16) packed[i] = make_int2(i >> 4, 0);
}

__global__ void count_kernel(const int* __restrict__ dst, int* __restrict__ cnt, int e) {
    int i = blockIdx.x * blockDim.x + threadIdx.x;
    if (i < e) atomicAdd(&cnt[dst[i]], 1);
}

__global__ __launch_bounds__(256) void partial_kernel(const int* __restrict__ cnt,
                                                      int* __restrict__ partial, int n) {
    const int b = blockIdx.x, t = threadIdx.x;
    const int base = b * 1024 + t * 4;
    int s = 0;
    if (base + 3 < n) {
        int4 c = *(const int4*)(cnt + base);
        s = c.x + c.y + c.z + c.w;
    } else {
        for (int j = 0; j < 4; ++j) if (base + j < n) s += cnt[base + j];
    }
    #pragma unroll
    for (int m = 1; m < 64; m <<= 1) s += __shfl_xor(s, m, 64);
    __shared__ int ws[4];
    if ((t & 63) == 0) ws[t >> 6] = s;
    __syncthreads();
    if (t == 0) partial[b] = ws[0] + ws[1] + ws[2] + ws[3];
}

__global__ __launch_bounds__(1024) void scan_partials_kernel(int* __restrict__ partial, int nb,
                                                             int* __restrict__ row_ptr,
                                                             int n, int e) {
    __shared__ int sh[1024];
    const int t = threadIdx.x;
    sh[t] = (t < nb) ? partial[t] : 0;
    __syncthreads();
    for (int off = 1; off < 1024; off <<= 1) {
        int v = (t >= off) ? sh[t - off] : 0;
        __syncthreads();
        sh[t] += v;
        __syncthreads();
    }
    if (t < nb) partial[t] = (t == 0) ? 0 : sh[t - 1];
    if (t == 0) row_ptr[n] = e;
}

__global__ __launch_bounds__(256) void emit_kernel(const int* __restrict__ cnt,
                                                   const int* __restrict__ partial,
                                                   int* __restrict__ row_ptr,
                                                   int* __restrict__ cursor,
                                                   float* __restrict__ dinv, int n) {
    const int b = blockIdx.x, t = threadIdx.x;
    const int base = b * 1024 + t * 4;
    int4 c = make_int4(0, 0, 0, 0);
    if (base + 3 < n) {
        c = *(const int4*)(cnt + base);
    } else {
        if (base     < n) c.x = cnt[base];
        if (base + 1 < n) c.y = cnt[base + 1];
        if (base + 2 < n) c.z = cnt[base + 2];
        if (base + 3 < n) c.w = cnt[base + 3];
    }
    const int ts = c.x + c.y + c.z + c.w;
    int incl = ts;
    const int lane = t & 63;
    #pragma unroll
    for (int off = 1; off < 64; off <<= 1) {
        int v = __shfl_up(incl, off, 64);
        if (lane >= off) incl += v;
    }
    __shared__ int wsum[4];
    if (lane == 63) wsum[t >> 6] = incl;
    __syncthreads();
    const int w = t >> 6;
    int waveoff = 0;
    #pragma unroll
    for (int i = 0; i < 3; ++i) if (i < w) waveoff += wsum[i];
    const int basev = partial[b] + waveoff + (incl - ts);
    const int e0 = basev, e1 = e0 + c.x, e2 = e1 + c.y, e3 = e2 + c.z;
    if (base + 3 < n) {
        *(int4*)(row_ptr + base) = make_int4(e0, e1, e2, e3);
        *(int4*)(cursor  + base) = make_int4(e0, e1, e2, e3);
        *(float4*)(dinv + base) = make_float4(rsqrtf((float)(c.x + 1)), rsqrtf((float)(c.y + 1)),
                                              rsqrtf((float)(c.z + 1)), rsqrtf((float)(c.w + 1)));
    } else {
        int es[4] = {e0, e1, e2, e3};
        int cs[4] = {c.x, c.y, c.z, c.w};
        for (int j = 0; j < 4; ++j) if (base + j < n) {
            row_ptr[base + j] = es[j];
            cursor[base + j]  = es[j];
            dinv[base + j]    = rsqrtf((float)(cs[j] + 1));
        }
    }
}

// fill CSR + packed table with precomputed per-edge weight {src, dinv[src]*dinv[dst]}
__global__ void fill_kernel(const int* __restrict__ src, const int* __restrict__ dst,
                            const float* __restrict__ dinv,
                            const int* __restrict__ row_ptr,
                            int* __restrict__ cursor, int2* __restrict__ meta,
                            int2* __restrict__ packed, int e) {
    int i = blockIdx.x * blockDim.x + threadIdx.x;
    if (i < e) {
        int s = src[i], d = dst[i];
        int p = atomicAdd(&cursor[d], 1);
        float w = dinv[s] * dinv[d];
        int2 rec = make_int2(s, __builtin_bit_cast(int, w));
        meta[p] = rec;
        int j = p - row_ptr[d];
        if (j < 16) packed[(size_t)d * 16 + j] = rec;
    }
}

// ---------------- W transpose+convert: Wt[l][n][k] = bf16(W[l][k][n]) ----------------
__global__ __launch_bounds__(256) void wt_prep_kernel(const float* __restrict__ W,
                                                      short* __restrict__ Wt, int total) {
    int o = blockIdx.x * blockDim.x + threadIdx.x;
    if (o >= total) return;
    int l = o >> 14;
    int r = o & 16383;
    int nn = r >> 7;
    int k  = r & 127;
    Wt[o] = f2bf(W[(size_t)l * 16384 + (size_t)k * 128 + nn]);
}

// ---------------- GEMM: H(bf16) = act @ W, A via LDS + B in VGPRs ----------------
template <bool IN_F32>
__global__ __launch_bounds__(256) void gemm_mfma_kernel(const void* __restrict__ Xv,
                                                        const short* __restrict__ Wt,
                                                        short* __restrict__ H, int n) {
    __shared__ short Alds[64 * AST];   // reused for the C transpose (64*CST fits)
    const int t    = threadIdx.x;
    const int wv   = t >> 6;
    const int lane = t & 63;
    const int m    = lane & 15;
    const int quad = lane >> 4;
    const int row0 = blockIdx.x * 64;

    // B fragments (registers): col = (wv*2+c)*16 + m, k = kt*32 + quad*8
    short8v bfr[2][4];
    #pragma unroll
    for (int c = 0; c < 2; ++c) {
        const short* bp = Wt + (size_t)((wv * 2 + c) * 16 + m) * D_DIM + quad * 8;
        #pragma unroll
        for (int kt = 0; kt < 4; ++kt)
            bfr[c][kt] = *(const short8v*)(bp + kt * 32);
    }

    // stage A tile in LDS (coalesced bulk)
    if constexpr (IN_F32) {
        const float* X = (const float*)Xv;
        #pragma unroll
        for (int i = 0; i < 8; ++i) {
            int q  = t + i * 256;     // float4 id (2048)
            int r  = q >> 5;
            int k4 = q & 31;
            int row = row0 + r;
            float4 v = make_float4(0.f, 0.f, 0.f, 0.f);
            if (row < n) v = *(const float4*)(X + (size_t)row * D_DIM + k4 * 4);
            short4v s;
            s.x = f2bf(v.x); s.y = f2bf(v.y); s.z = f2bf(v.z); s.w = f2bf(v.w);
            *(short4v*)(&Alds[r * AST + k4 * 4]) = s;
        }
    } else {
        const short* X = (const short*)Xv;
        #pragma unroll
        for (int i = 0; i < 4; ++i) {
            int q  = t + i * 256;     // short8 id (1024)
            int r  = q >> 4;
            int kc = q & 15;
            int row = row0 + r;
            short8v v = {0,0,0,0,0,0,0,0};
            if (row < n) v = *(const short8v*)(X + (size_t)row * D_DIM + kc * 8);
            *(short8v*)(&Alds[r * AST + kc * 8]) = v;
        }
    }
    __syncthreads();

    floatx4 acc[4][2];
    #pragma unroll
    for (int rt = 0; rt < 4; ++rt) {
        const short* ab = &Alds[(rt * 16 + m) * AST + quad * 8];
        short8v afr[4];
        #pragma unroll
        for (int kt = 0; kt < 4; ++kt) afr[kt] = *(const short8v*)(ab + kt * 32);

        #pragma unroll
        for (int c = 0; c < 2; ++c) {
            floatx4 a = (floatx4){0.f, 0.f, 0.f, 0.f};
            #pragma unroll
            for (int kt = 0; kt < 4; ++kt)
                a = __builtin_amdgcn_mfma_f32_16x16x32_bf16(afr[kt], bfr[c][kt], a, 0, 0, 0);
            acc[rt][c] = a;
        }
    }
    __syncthreads();   // all A reads done; reuse LDS for C

    // C/D: col = (wv*2+c)*16 + m, row = rt*16 + quad*4 + r  -> LDS transpose
    #pragma unroll
    for (int rt = 0; rt < 4; ++rt) {
        #pragma unroll
        for (int c = 0; c < 2; ++c) {
            const int col = (wv * 2 + c) * 16 + m;
            #pragma unroll
            for (int r = 0; r < 4; ++r)
                Alds[(rt * 16 + quad * 4 + r) * CST + col] = f2bf(acc[rt][c][r]);
        }
    }
    __syncthreads();

    // coalesced stores: 16 lanes cover a full 256B row
    #pragma unroll
    for (int i = 0; i < 4; ++i) {
        int q  = t + i * 256;     // short8 id (1024)
        int r  = q >> 4;
        int kc = q & 15;
        int row = row0 + r;
        if (row < n)
            *(short8v*)(H + (size_t)row * D_DIM + kc * 8) = *(const short8v*)(&Alds[r * CST + kc * 8]);
    }
}

// ---------------- Aggregation + bias + ReLU + LayerNorm ----------------
// One wave per TWO consecutive nodes. Fixed-stride packed edge table removes the
// row_ptr->meta dependency: mm = packed[vA*16 + (lane&31)] covers edges 0..15 of
// BOTH nodes with ONE load and no prior round trip. All slots are valid (pad
// slots = {self, w=0}) so the fast path is BRANCHLESS: 32 gathers issue
// back-to-back before any FMA (max memory-level parallelism). Chain is 2 serial
// round trips (packed -> gathers). Rare deg>16 tail falls back to CSR meta.
template <bool OUT_BF16>
__global__ __launch_bounds__(256) void agg_kernel(const short* __restrict__ Hb,
                                                  const int2* __restrict__ packed,
                                                  const int* __restrict__ cnt,
                                                  const int* __restrict__ row_ptr,
                                                  const int2* __restrict__ meta,
                                                  const float* __restrict__ dinv,
                                                  const float* __restrict__ bias,
                                                  const float* __restrict__ gamma,
                                                  const float* __restrict__ beta,
                                                  void* __restrict__ Yv, int n) {
    const int wave = __builtin_amdgcn_readfirstlane(threadIdx.x >> 6);
    const int lane = threadIdx.x & 63;
    const int vA = (blockIdx.x * 4 + wave) * 2;
    if (vA >= n) return;
    const bool hasB = (vA + 1) < n;
    const int vB = hasB ? vA + 1 : vA;

    // --- independent early loads (all issue together, no dependencies) ---
    const int2   cc  = *(const int2*)(cnt + vA);        // degrees (vA even -> 8B aligned)
    const float2 dv2 = *(const float2*)(dinv + vA);
    const float2 bb  = ((const float2*)bias)[lane];     // hoisted LN params
    const float2 gg  = ((const float2*)gamma)[lane];
    const float2 be  = ((const float2*)beta)[lane];
    // one 8B/lane load (lanes 0-31) covers packed meta for edges 0..15 of both nodes
    const int2 mm = packed[(size_t)vA * 16 + (lane & 31)];
    // self rows
    const unsigned psA = ((const unsigned*)(Hb + (size_t)vA * D_DIM))[lane];
    const unsigned psB = ((const unsigned*)(Hb + (size_t)vB * D_DIM))[lane];

    const float dvA = dv2.x;
    const float dvB = hasB ? dv2.y : dv2.x;

    float axA = bflo(psA) * (dvA * dvA);
    float ayA = bfhi(psA) * (dvA * dvA);
    float axB = bflo(psB) * (dvB * dvB);
    float ayB = bfhi(psB) * (dvB * dvB);

    // --- issue ALL 32 gathers before any FMA (branchless, pad slots hit L1) ---
    unsigned p[32];
    #pragma unroll
    for (int j = 0; j < 16; ++j) {
        const int s = __builtin_amdgcn_readlane(mm.x, j);
        p[j] = ((const unsigned*)(Hb + (size_t)s * D_DIM))[lane];
    }
    if (hasB) {
        #pragma unroll
        for (int j = 0; j < 16; ++j) {
            const int s = __builtin_amdgcn_readlane(mm.x, 16 + j);
            p[16 + j] = ((const unsigned*)(Hb + (size_t)s * D_DIM))[lane];
        }
    } else {
        #pragma unroll
        for (int j = 0; j < 16; ++j) p[16 + j] = 0u;
    }

    // --- accumulate ---
    #pragma unroll
    for (int j = 0; j < 16; ++j) {
        const float wA = __builtin_bit_cast(float, __builtin_amdgcn_readlane(mm.y, j));
        const float wB = hasB ? __builtin_bit_cast(float, __builtin_amdgcn_readlane(mm.y, 16 + j)) : 0.f;
        axA = fmaf(wA, bflo(p[j]), axA);
        ayA = fmaf(wA, bfhi(p[j]), ayA);
        axB = fmaf(wB, bflo(p[16 + j]), axB);
        ayB = fmaf(wB, bfhi(p[16 + j]), ayB);
    }

    // --- rare tail: deg > 16 (Poisson(6): ~1e-4 of nodes) via CSR meta ---
    const int cntA = cc.x;
    const int cntB = hasB ? cc.y : 0;
    if ((cntA > 16) | (cntB > 16)) {
        const int begA = __builtin_amdgcn_readfirstlane(row_ptr[vA]);
        const int endA = begA + cntA;
        const int begB = __builtin_amdgcn_readfirstlane(row_ptr[vB]);
        const int endB = begB + cntB;
        const int mx = cntA > cntB ? cntA : cntB;
        for (int k = 16; k < mx; k += 4) {
            int   idx[8];
            float wgt[8];
            #pragma unroll
            for (int j = 0; j < 4; ++j) {
                int ii = min(begA + k + j, endA - 1); ii = max(ii, begA);
                const int2 m2 = meta[ii];
                idx[j] = m2.x;
                wgt[j] = (k + j < cntA) ? __builtin_bit_cast(float, m2.y) : 0.f;
            }
            #pragma unroll
            for (int j = 0; j < 4; ++j) {
                int ii = min(begB + k + j, endB - 1); ii = max(ii, begB);
                const int2 m2 = meta[ii];
                idx[4 + j] = m2.x;
                wgt[4 + j] = (k + j < cntB) ? __builtin_bit_cast(float, m2.y) : 0.f;
            }
            unsigned q[8];
            #pragma unroll
            for (int j = 0; j < 8; ++j)
                q[j] = ((const unsigned*)(Hb + (size_t)idx[j] * D_DIM))[lane];
            #pragma unroll
            for (int j = 0; j < 4; ++j) {
                axA = fmaf(wgt[j], bflo(q[j]), axA);
                ayA = fmaf(wgt[j], bfhi(q[j]), ayA);
                axB = fmaf(wgt[4 + j], bflo(q[4 + j]), axB);
                ayB = fmaf(wgt[4 + j], bfhi(q[4 + j]), ayB);
            }
        }
    }

    // --- bias + ReLU + LayerNorm epilogue ---
    #pragma unroll
    for (int s = 0; s < 2; ++s) {
        if (s == 1 && !hasB) break;
        float a0 = fmaxf((s ? axB : axA) + bb.x, 0.f);
        float a1 = fmaxf((s ? ayB : ayA) + bb.y, 0.f);
        float s1 = a0 + a1;
        float s2 = a0 * a0 + a1 * a1;
        #pragma unroll
        for (int m = 1; m < 64; m <<= 1) {
            s1 += __shfl_xor(s1, m, 64);
            s2 += __shfl_xor(s2, m, 64);
        }
        const float mu  = s1 * (1.f / 128.f);
        const float var = s2 * (1.f / 128.f) - mu * mu;
        const float rs  = rsqrtf(var + 1e-5f);
        const float o0 = (a0 - mu) * rs * gg.x + be.x;
        const float o1 = (a1 - mu) * rs * gg.y + be.y;
        const int v = s ? vB : vA;
        if constexpr (OUT_BF16) {
            unsigned pack = (unsigned)(unsigned short)f2bf(o0) |
                            ((unsigned)(unsigned short)f2bf(o1) << 16);
            ((unsigned*)((short*)Yv + (size_t)v * D_DIM))[lane] = pack;
        } else {
            float2 o; o.x = o0; o.y = o1;
            ((float2*)((float*)Yv + (size_t)v * D_DIM))[lane] = o;
        }
    }
}

// ---------------- launch ----------------

extern "C" void kernel_launch(void* const* d_in, const int* in_sizes, int n_in,
                              void* d_out, int out_size, void* d_ws, size_t ws_size,
                              hipStream_t stream) {
    const float* x     = (const float*)d_in[0];
    const float* W     = (const float*)d_in[1];
    const float* bias  = (const float*)d_in[2];
    const float* gamma = (const float*)d_in[3];
    const float* beta  = (const float*)d_in[4];
    const int*   edges = (const int*)d_in[5];

    const int N = in_sizes[0] / D_DIM;
    const int E = in_sizes[5] / 2;
    const int L = in_sizes[1] / (D_DIM * D_DIM);

    const int* src = edges;
    const int* dst = edges + E;

    const int NB = (N + 1023) / 1024;

    // workspace carve — 16B alignment maintained
    char* w = (char*)d_ws;
    short* Hb    = (short*)w; w += (size_t)N * D_DIM * sizeof(short);
    short* Act   = (short*)w; w += (size_t)N * D_DIM * sizeof(short);
    int* cnt     = (int*)w;  w += (size_t)((N + 3) & ~3) * sizeof(int);
    int* row_ptr = (int*)w;  w += (size_t)((N + 4) & ~3) * sizeof(int);
    int* cursor  = (int*)w;  w += (size_t)((N + 3) & ~3) * sizeof(int);
    int2* meta   = (int2*)w; w += (size_t)E * sizeof(int2);
    int2* packed = (int2*)w; w += (size_t)N * 16 * sizeof(int2);
    float* dinv  = (float*)w; w += (size_t)((N + 3) & ~3) * sizeof(float);
    int* partial = (int*)w;  w += (size_t)((NB + 3) & ~3) * sizeof(int);
    short* Wt    = (short*)w; w += (size_t)L * D_DIM * D_DIM * sizeof(short);

    // CSR + packed-table build
    zero_cnt_kernel<<<(N + 255) / 256, 256, 0, stream>>>(cnt, N);
    packed_init_kernel<<<(N * 16 + 255) / 256, 256, 0, stream>>>(packed, N * 16);
    count_kernel<<<(E + 255) / 256, 256, 0, stream>>>(dst, cnt, E);
    partial_kernel<<<NB, 256, 0, stream>>>(cnt, partial, N);
    scan_partials_kernel<<<1, 1024, 0, stream>>>(partial, NB, row_ptr, N, E);
    emit_kernel<<<NB, 256, 0, stream>>>(cnt, partial, row_ptr, cursor, dinv, N);
    fill_kernel<<<(E + 255) / 256, 256, 0, stream>>>(src, dst, dinv, row_ptr,
                                                     cursor, meta, packed, E);

    // W -> bf16 transpose (once per call)
    const int WT_TOTAL = L * D_DIM * D_DIM;
    wt_prep_kernel<<<(WT_TOTAL + 255) / 256, 256, 0, stream>>>(W, Wt, WT_TOTAL);

    const int GB = (N + 63) / 64;
    const int AB = (N + 7) / 8;   // 4 waves/block x 2 nodes/wave

    // layer 0: f32 x -> H(bf16) -> Act(bf16)
    gemm_mfma_kernel<true><<<GB, 256, 0, stream>>>(x, Wt, Hb, N);
    agg_kernel<true><<<AB, 256, 0, stream>>>(Hb, packed, cnt, row_ptr, meta, dinv,
                                             bias, gamma, beta, Act, N);
    // layers 1..L-2: bf16 -> bf16
    for (int l = 1; l < L - 1; ++l) {
        gemm_mfma_kernel<false><<<GB, 256, 0, stream>>>(Act, Wt + (size_t)l * D_DIM * D_DIM, Hb, N);
        agg_kernel<true><<<AB, 256, 0, stream>>>(Hb, packed, cnt, row_ptr, meta, dinv,
                                                 bias + (size_t)l * D_DIM,
                                                 gamma + (size_t)l * D_DIM,
                                                 beta + (size_t)l * D_DIM, Act, N);
    }
    // final layer: bf16 -> f32 d_out
    {
        int l = L - 1;
        gemm_mfma_kernel<false><<<GB, 256, 0, stream>>>(Act, Wt + (size_t)l * D_DIM * D_DIM, Hb, N);
        agg_kernel<false><<<AB, 256, 0, stream>>>(Hb, packed, cnt, row_ptr, meta, dinv,
                                                  bias + (size_t)l * D_DIM,
                                                  gamma + (size_t)l * D_DIM,
                                                  beta + (size_t)l * D_DIM, d_out, N);
    }
}

// Round 3
// 341.260 us; speedup vs baseline: 1.1321x; 1.1321x over previous
//
#include <hip/hip_runtime.h>
#include <hip/hip_bf16.h>

#define D_DIM 128
#define AST 136   // padded LDS row stride (shorts) for the A tile
#define CST 132   // padded LDS row stride (shorts) for the C transpose

typedef __attribute__((ext_vector_type(8))) short short8v;
typedef __attribute__((ext_vector_type(4))) short short4v;
typedef __attribute__((ext_vector_type(4))) float floatx4;

__device__ __forceinline__ short f2bf(float x) {
    unsigned u = __builtin_bit_cast(unsigned, x);
    unsigned r = u + 0x7fff + ((u >> 16) & 1);   // RNE
    return (short)(r >> 16);
}
__device__ __forceinline__ float bflo(unsigned p) {
    return __builtin_bit_cast(float, p << 16);
}
__device__ __forceinline__ float bfhi(unsigned p) {
    return __builtin_bit_cast(float, p & 0xffff0000u);
}

// ---------------- build: single pass, no CSR ----------------
// packed[v*16+j] = src of j-th incoming edge (src only, 4B). Pad slots = v
// (self row, L1-hot, weight forced to 0 via deg). Edges beyond 16/node go to a
// tiny overflow list (Poisson(6): ~30 entries total).

__global__ __launch_bounds__(256) void init_kernel(int* __restrict__ deg,
                                                   int* __restrict__ packedi,
                                                   int* __restrict__ ovcnt, int n16) {
    int i = blockIdx.x * blockDim.x + threadIdx.x;
    if (i < n16) {
        packedi[i] = i >> 4;
        if ((i & 15) == 0) deg[i >> 4] = 0;
    }
    if (i == 0) *ovcnt = 0;
}

__global__ void fill2_kernel(const int* __restrict__ src, const int* __restrict__ dst,
                             int* __restrict__ deg, int* __restrict__ packedi,
                             int2* __restrict__ ov, int* __restrict__ ovcnt, int e) {
    int i = blockIdx.x * blockDim.x + threadIdx.x;
    if (i >= e) return;
    int s = src[i], d = dst[i];
    int j = atomicAdd(&deg[d], 1);
    if (j < 16) {
        packedi[(size_t)d * 16 + j] = s;
    } else {
        int k = atomicAdd(ovcnt, 1);
        ov[k] = make_int2(d, s);
    }
}

__global__ void dinv_kernel(const int* __restrict__ deg, float* __restrict__ dinv, int n) {
    int i = blockIdx.x * blockDim.x + threadIdx.x;
    if (i < n) dinv[i] = rsqrtf((float)deg[i] + 1.0f);
}

// ---------------- W transpose+convert: Wt[l][n][k] = bf16(W[l][k][n]) ----------------
__global__ __launch_bounds__(256) void wt_prep_kernel(const float* __restrict__ W,
                                                      short* __restrict__ Wt, int total) {
    int o = blockIdx.x * blockDim.x + threadIdx.x;
    if (o >= total) return;
    int l = o >> 14;
    int r = o & 16383;
    int nn = r >> 7;
    int k  = r & 127;
    Wt[o] = f2bf(W[(size_t)l * 16384 + (size_t)k * 128 + nn]);
}

// ---------------- GEMM: H(bf16) = act @ W, A via LDS + B in VGPRs ----------------
template <bool IN_F32>
__global__ __launch_bounds__(256) void gemm_mfma_kernel(const void* __restrict__ Xv,
                                                        const short* __restrict__ Wt,
                                                        short* __restrict__ H, int n) {
    __shared__ short Alds[64 * AST];   // reused for the C transpose (64*CST fits)
    const int t    = threadIdx.x;
    const int wv   = t >> 6;
    const int lane = t & 63;
    const int m    = lane & 15;
    const int quad = lane >> 4;
    const int row0 = blockIdx.x * 64;

    // B fragments (registers): col = (wv*2+c)*16 + m, k = kt*32 + quad*8
    short8v bfr[2][4];
    #pragma unroll
    for (int c = 0; c < 2; ++c) {
        const short* bp = Wt + (size_t)((wv * 2 + c) * 16 + m) * D_DIM + quad * 8;
        #pragma unroll
        for (int kt = 0; kt < 4; ++kt)
            bfr[c][kt] = *(const short8v*)(bp + kt * 32);
    }

    // stage A tile in LDS (coalesced bulk)
    if constexpr (IN_F32) {
        const float* X = (const float*)Xv;
        #pragma unroll
        for (int i = 0; i < 8; ++i) {
            int q  = t + i * 256;     // float4 id (2048)
            int r  = q >> 5;
            int k4 = q & 31;
            int row = row0 + r;
            float4 v = make_float4(0.f, 0.f, 0.f, 0.f);
            if (row < n) v = *(const float4*)(X + (size_t)row * D_DIM + k4 * 4);
            short4v s;
            s.x = f2bf(v.x); s.y = f2bf(v.y); s.z = f2bf(v.z); s.w = f2bf(v.w);
            *(short4v*)(&Alds[r * AST + k4 * 4]) = s;
        }
    } else {
        const short* X = (const short*)Xv;
        #pragma unroll
        for (int i = 0; i < 4; ++i) {
            int q  = t + i * 256;     // short8 id (1024)
            int r  = q >> 4;
            int kc = q & 15;
            int row = row0 + r;
            short8v v = {0,0,0,0,0,0,0,0};
            if (row < n) v = *(const short8v*)(X + (size_t)row * D_DIM + kc * 8);
            *(short8v*)(&Alds[r * AST + kc * 8]) = v;
        }
    }
    __syncthreads();

    floatx4 acc[4][2];
    #pragma unroll
    for (int rt = 0; rt < 4; ++rt) {
        const short* ab = &Alds[(rt * 16 + m) * AST + quad * 8];
        short8v afr[4];
        #pragma unroll
        for (int kt = 0; kt < 4; ++kt) afr[kt] = *(const short8v*)(ab + kt * 32);

        #pragma unroll
        for (int c = 0; c < 2; ++c) {
            floatx4 a = (floatx4){0.f, 0.f, 0.f, 0.f};
            #pragma unroll
            for (int kt = 0; kt < 4; ++kt)
                a = __builtin_amdgcn_mfma_f32_16x16x32_bf16(afr[kt], bfr[c][kt], a, 0, 0, 0);
            acc[rt][c] = a;
        }
    }
    __syncthreads();   // all A reads done; reuse LDS for C

    // C/D: col = (wv*2+c)*16 + m, row = rt*16 + quad*4 + r  -> LDS transpose
    #pragma unroll
    for (int rt = 0; rt < 4; ++rt) {
        #pragma unroll
        for (int c = 0; c < 2; ++c) {
            const int col = (wv * 2 + c) * 16 + m;
            #pragma unroll
            for (int r = 0; r < 4; ++r)
                Alds[(rt * 16 + quad * 4 + r) * CST + col] = f2bf(acc[rt][c][r]);
        }
    }
    __syncthreads();

    // coalesced stores: 16 lanes cover a full 256B row
    #pragma unroll
    for (int i = 0; i < 4; ++i) {
        int q  = t + i * 256;     // short8 id (1024)
        int r  = q >> 4;
        int kc = q & 15;
        int row = row0 + r;
        if (row < n)
            *(short8v*)(H + (size_t)row * D_DIM + kc * 8) = *(const short8v*)(&Alds[r * CST + kc * 8]);
    }
}

// ---------------- Aggregation + bias + ReLU + LayerNorm ----------------
// One wave per TWO consecutive nodes. packed (src-only, 4B) loaded with one
// lane-distributed read; src broadcast via readlane -> SGPR base gathers.
// Factored weights: out = dv_d*(dv_d*h_self + sum dinv[s_j]*h_j) so per-edge
// weight is a SCALAR load (SMEM pipe) + s_cselect zeroing — no vmem, no VALU.
// Chunk guards: slots 0-7 always, 8-11 if max>8, 12-15 if max>12 — keeps the
// vmem instruction count near the true edge count. deg>16 tail via tiny
// overflow list (wave-uniform scan, only entered when a node has deg>16).
template <bool OUT_BF16>
__global__ __launch_bounds__(256) void agg_kernel(const short* __restrict__ Hb,
                                                  const int* __restrict__ packedi,
                                                  const int* __restrict__ deg,
                                                  const float* __restrict__ dinv,
                                                  const int2* __restrict__ ov,
                                                  const int* __restrict__ ovcnt,
                                                  const float* __restrict__ bias,
                                                  const float* __restrict__ gamma,
                                                  const float* __restrict__ beta,
                                                  void* __restrict__ Yv, int n) {
    const int wave = __builtin_amdgcn_readfirstlane(threadIdx.x >> 6);
    const int lane = threadIdx.x & 63;
    const int vA = (blockIdx.x * 4 + wave) * 2;
    if (vA >= n) return;
    const bool hasB = (vA + 1) < n;
    const int vB = hasB ? vA + 1 : vA;

    // wave-uniform scalars (scalar loads)
    const int cntA = deg[vA];
    const int cntB = hasB ? deg[vB] : 0;
    const float dvA = dinv[vA];
    const float dvB = dinv[vB];

    // per-lane loads (all independent, issue together)
    const int sl = lane & 31;
    const int pk = packedi[(size_t)vA * 16 + (hasB ? sl : (sl & 15))];
    const float2 bb = ((const float2*)bias)[lane];
    const float2 gg = ((const float2*)gamma)[lane];
    const float2 be = ((const float2*)beta)[lane];
    const unsigned psA = ((const unsigned*)(Hb + (size_t)vA * D_DIM))[lane];
    const unsigned psB = ((const unsigned*)(Hb + (size_t)vB * D_DIM))[lane];

    // factored accumulation: out_pre = dv*(dv*h_self + sum_j dinv[s_j]*h_j)
    float axA = bflo(psA) * dvA;
    float ayA = bfhi(psA) * dvA;
    float axB = bflo(psB) * dvB;
    float ayB = bfhi(psB) * dvB;

    unsigned p[16];
    float    w[16];
    // ---- slots 0-7 (covers ~78% of nodes fully) ----
    #pragma unroll
    for (int j = 0; j < 8; ++j) {
        const int sA = __builtin_amdgcn_readlane(pk, j);
        const int sB = __builtin_amdgcn_readlane(pk, 16 + j);
        p[j]     = ((const unsigned*)(Hb + (size_t)sA * D_DIM))[lane];
        p[8 + j] = ((const unsigned*)(Hb + (size_t)sB * D_DIM))[lane];
        w[j]     = (j < cntA) ? dinv[sA] : 0.f;
        w[8 + j] = (j < cntB) ? dinv[sB] : 0.f;
    }
    #pragma unroll
    for (int j = 0; j < 8; ++j) {
        axA = fmaf(w[j], bflo(p[j]), axA);
        ayA = fmaf(w[j], bfhi(p[j]), ayA);
        axB = fmaf(w[8 + j], bflo(p[8 + j]), axB);
        ayB = fmaf(w[8 + j], bfhi(p[8 + j]), ayB);
    }
    // ---- slots 8-11 (~28% of pairs) ----
    if ((cntA > 8) | (cntB > 8)) {
        #pragma unroll
        for (int j = 0; j < 4; ++j) {
            const int sA = __builtin_amdgcn_readlane(pk, 8 + j);
            const int sB = __builtin_amdgcn_readlane(pk, 24 + j);
            p[j]     = ((const unsigned*)(Hb + (size_t)sA * D_DIM))[lane];
            p[4 + j] = ((const unsigned*)(Hb + (size_t)sB * D_DIM))[lane];
            w[j]     = (8 + j < cntA) ? dinv[sA] : 0.f;
            w[4 + j] = (8 + j < cntB) ? dinv[sB] : 0.f;
        }
        #pragma unroll
        for (int j = 0; j < 4; ++j) {
            axA = fmaf(w[j], bflo(p[j]), axA);
            ayA = fmaf(w[j], bfhi(p[j]), ayA);
            axB = fmaf(w[4 + j], bflo(p[4 + j]), axB);
            ayB = fmaf(w[4 + j], bfhi(p[4 + j]), ayB);
        }
        // ---- slots 12-15 (~2% of pairs) ----
        if ((cntA > 12) | (cntB > 12)) {
            #pragma unroll
            for (int j = 0; j < 4; ++j) {
                const int sA = __builtin_amdgcn_readlane(pk, 12 + j);
                const int sB = __builtin_amdgcn_readlane(pk, 28 + j);
                p[j]     = ((const unsigned*)(Hb + (size_t)sA * D_DIM))[lane];
                p[4 + j] = ((const unsigned*)(Hb + (size_t)sB * D_DIM))[lane];
                w[j]     = (12 + j < cntA) ? dinv[sA] : 0.f;
                w[4 + j] = (12 + j < cntB) ? dinv[sB] : 0.f;
            }
            #pragma unroll
            for (int j = 0; j < 4; ++j) {
                axA = fmaf(w[j], bflo(p[j]), axA);
                ayA = fmaf(w[j], bfhi(p[j]), ayA);
                axB = fmaf(w[4 + j], bflo(p[4 + j]), axB);
                ayB = fmaf(w[4 + j], bfhi(p[4 + j]), ayB);
            }
        }
        // ---- deg>16 overflow (~0.03% of waves scan the tiny list) ----
        if ((cntA > 16) | (cntB > 16)) {
            const int oc = *ovcnt;
            for (int k = 0; k < oc; ++k) {
                const int2 eo = ov[k];
                if ((eo.x == vA) | (eo.x == vB)) {
                    const float ws = dinv[eo.y];
                    const unsigned q = ((const unsigned*)(Hb + (size_t)eo.y * D_DIM))[lane];
                    if (eo.x == vA) {
                        axA = fmaf(ws, bflo(q), axA);
                        ayA = fmaf(ws, bfhi(q), ayA);
                    } else {
                        axB = fmaf(ws, bflo(q), axB);
                        ayB = fmaf(ws, bfhi(q), ayB);
                    }
                }
            }
        }
    }

    // --- bias + ReLU + LayerNorm epilogue ---
    #pragma unroll
    for (int s = 0; s < 2; ++s) {
        if (s == 1 && !hasB) break;
        const float dv = s ? dvB : dvA;
        float a0 = fmaxf(fmaf(dv, (s ? axB : axA), bb.x), 0.f);
        float a1 = fmaxf(fmaf(dv, (s ? ayB : ayA), bb.y), 0.f);
        float s1 = a0 + a1;
        float s2 = a0 * a0 + a1 * a1;
        #pragma unroll
        for (int m = 1; m < 64; m <<= 1) {
            s1 += __shfl_xor(s1, m, 64);
            s2 += __shfl_xor(s2, m, 64);
        }
        const float mu  = s1 * (1.f / 128.f);
        const float var = s2 * (1.f / 128.f) - mu * mu;
        const float rs  = rsqrtf(var + 1e-5f);
        const float o0 = (a0 - mu) * rs * gg.x + be.x;
        const float o1 = (a1 - mu) * rs * gg.y + be.y;
        const int v = s ? vB : vA;
        if constexpr (OUT_BF16) {
            unsigned pack = (unsigned)(unsigned short)f2bf(o0) |
                            ((unsigned)(unsigned short)f2bf(o1) << 16);
            ((unsigned*)((short*)Yv + (size_t)v * D_DIM))[lane] = pack;
        } else {
            float2 o; o.x = o0; o.y = o1;
            ((float2*)((float*)Yv + (size_t)v * D_DIM))[lane] = o;
        }
    }
}

// ---------------- launch ----------------

extern "C" void kernel_launch(void* const* d_in, const int* in_sizes, int n_in,
                              void* d_out, int out_size, void* d_ws, size_t ws_size,
                              hipStream_t stream) {
    const float* x     = (const float*)d_in[0];
    const float* W     = (const float*)d_in[1];
    const float* bias  = (const float*)d_in[2];
    const float* gamma = (const float*)d_in[3];
    const float* beta  = (const float*)d_in[4];
    const int*   edges = (const int*)d_in[5];

    const int N = in_sizes[0] / D_DIM;
    const int E = in_sizes[5] / 2;
    const int L = in_sizes[1] / (D_DIM * D_DIM);

    const int* src = edges;
    const int* dst = edges + E;

    // workspace carve — 16B alignment maintained
    char* w = (char*)d_ws;
    short* Hb      = (short*)w; w += (size_t)N * D_DIM * sizeof(short);
    short* Act     = (short*)w; w += (size_t)N * D_DIM * sizeof(short);
    int*   deg     = (int*)w;   w += (size_t)((N + 3) & ~3) * sizeof(int);
    int*   packedi = (int*)w;   w += (size_t)N * 16 * sizeof(int);
    float* dinv    = (float*)w; w += (size_t)((N + 3) & ~3) * sizeof(float);
    int2*  ov      = (int2*)w;  w += (size_t)E * sizeof(int2);
    int*   ovcnt   = (int*)w;   w += 16;
    short* Wt      = (short*)w; w += (size_t)L * D_DIM * D_DIM * sizeof(short);

    // single-pass build (no CSR)
    init_kernel<<<(N * 16 + 255) / 256, 256, 0, stream>>>(deg, packedi, ovcnt, N * 16);
    fill2_kernel<<<(E + 255) / 256, 256, 0, stream>>>(src, dst, deg, packedi, ov, ovcnt, E);
    dinv_kernel<<<(N + 255) / 256, 256, 0, stream>>>(deg, dinv, N);

    // W -> bf16 transpose (once per call)
    const int WT_TOTAL = L * D_DIM * D_DIM;
    wt_prep_kernel<<<(WT_TOTAL + 255) / 256, 256, 0, stream>>>(W, Wt, WT_TOTAL);

    const int GB = (N + 63) / 64;
    const int AB = (N + 7) / 8;   // 4 waves/block x 2 nodes/wave

    // layer 0: f32 x -> H(bf16) -> Act(bf16)
    gemm_mfma_kernel<true><<<GB, 256, 0, stream>>>(x, Wt, Hb, N);
    agg_kernel<true><<<AB, 256, 0, stream>>>(Hb, packedi, deg, dinv, ov, ovcnt,
                                             bias, gamma, beta, Act, N);
    // layers 1..L-2: bf16 -> bf16
    for (int l = 1; l < L - 1; ++l) {
        gemm_mfma_kernel<false><<<GB, 256, 0, stream>>>(Act, Wt + (size_t)l * D_DIM * D_DIM, Hb, N);
        agg_kernel<true><<<AB, 256, 0, stream>>>(Hb, packedi, deg, dinv, ov, ovcnt,
                                                 bias + (size_t)l * D_DIM,
                                                 gamma + (size_t)l * D_DIM,
                                                 beta + (size_t)l * D_DIM, Act, N);
    }
    // final layer: bf16 -> f32 d_out
    {
        int l = L - 1;
        gemm_mfma_kernel<false><<<GB, 256, 0, stream>>>(Act, Wt + (size_t)l * D_DIM * D_DIM, Hb, N);
        agg_kernel<false><<<AB, 256, 0, stream>>>(Hb, packedi, deg, dinv, ov, ovcnt,
                                                  bias + (size_t)l * D_DIM,
                                                  gamma + (size_t)l * D_DIM,
                                                  beta + (size_t)l * D_DIM, d_out, N);
    }
}